// Round 1
// baseline (515.724 us; speedup 1.0000x reference)
//
#include <hip/hip_runtime.h>
#include <hip/hip_bf16.h>
#include <math.h>

#define N_NODES 10000
#define N_EDGES 160000
#define ET      (N_EDGES + N_NODES)   // with self loops
#define D_INF   768
#define D_HID   128
#define HEADS   4

// ---------------------------------------------------------------------------
// Generic row-panel GEMM: out[N,M] = in[N,K] @ W[K,M] (+ bias)
// Block: M threads, RWS rows per block staged in dynamic LDS.
// W column reads are coalesced across threads and L2-resident.
// ---------------------------------------------------------------------------
template<int K, int M, int RWS>
__global__ void gemm_rows_kernel(const float* __restrict__ in,
                                 const float* __restrict__ W,
                                 const float* __restrict__ bias,
                                 float* __restrict__ out) {
    int row0 = blockIdx.x * RWS;
    extern __shared__ float lr[];   // RWS * K floats
    for (int i = threadIdx.x; i < RWS * K; i += M)
        lr[i] = in[row0 * K + i];
    __syncthreads();
    float acc[RWS];
#pragma unroll
    for (int r = 0; r < RWS; ++r) acc[r] = 0.0f;
#pragma unroll 4
    for (int k = 0; k < K; ++k) {
        float w = W[k * M + threadIdx.x];
#pragma unroll
        for (int r = 0; r < RWS; ++r) acc[r] += lr[r * K + k] * w;
    }
    float bb = bias ? bias[threadIdx.x] : 0.0f;
#pragma unroll
    for (int r = 0; r < RWS; ++r)
        out[(row0 + r) * M + threadIdx.x] = acc[r] + bb;
}

// ---------------------------------------------------------------------------
// Per-node attention logits: as[n,h] = sum_c h[n,h,c]*att_src[h,c]  (same dst)
// Block: H*128 threads, one node per block.
// ---------------------------------------------------------------------------
template<int H>
__global__ void att_kernel(const float* __restrict__ h,
                           const float* __restrict__ att_src,
                           const float* __restrict__ att_dst,
                           float* __restrict__ as, float* __restrict__ ad) {
    int n = blockIdx.x;
    int tid = threadIdx.x;
    float v = h[n * (H * 128) + tid];
    __shared__ float rs[H * 128];
    __shared__ float rd[H * 128];
    rs[tid] = v * att_src[tid];
    rd[tid] = v * att_dst[tid];
    __syncthreads();
    for (int s = 64; s > 0; s >>= 1) {
        if ((tid & 127) < s) { rs[tid] += rs[tid + s]; rd[tid] += rd[tid + s]; }
        __syncthreads();
    }
    if ((tid & 127) == 0) {
        int hd = tid >> 7;
        as[n * H + hd] = rs[tid];
        ad[n * H + hd] = rd[tid];
    }
}

// ---------------------------------------------------------------------------
// CSR build (by dst)
// ---------------------------------------------------------------------------
__global__ void zero_int_kernel(int* __restrict__ p, int n) {
    int i = blockIdx.x * blockDim.x + threadIdx.x;
    if (i < n) p[i] = 0;
}

__global__ void deg_kernel(const int* __restrict__ ei, int* __restrict__ deg) {
    int e = blockIdx.x * blockDim.x + threadIdx.x;
    if (e >= ET) return;
    int d = (e < N_EDGES) ? ei[N_EDGES + e] : (e - N_EDGES);
    atomicAdd(&deg[d], 1);
}

__global__ void scan_kernel(const int* __restrict__ deg,
                            int* __restrict__ off, int* __restrict__ cur) {
    __shared__ int tmp[1024];
    __shared__ int carry;
    int tid = threadIdx.x;
    if (tid == 0) carry = 0;
    __syncthreads();
    for (int base = 0; base < N_NODES; base += 1024) {
        int i = base + tid;
        int v = (i < N_NODES) ? deg[i] : 0;
        tmp[tid] = v;
        __syncthreads();
        for (int s = 1; s < 1024; s <<= 1) {
            int t = (tid >= s) ? tmp[tid - s] : 0;
            __syncthreads();
            tmp[tid] += t;
            __syncthreads();
        }
        int incl = tmp[tid];
        int ex = carry + incl - v;
        if (i < N_NODES) { off[i] = ex; cur[i] = ex; }
        __syncthreads();
        if (tid == 1023) carry += incl;
        __syncthreads();
    }
    if (tid == 0) off[N_NODES] = carry;
}

__global__ void fill_kernel(const int* __restrict__ ei,
                            int* __restrict__ cur, int* __restrict__ csr_src) {
    int e = blockIdx.x * blockDim.x + threadIdx.x;
    if (e >= ET) return;
    int s, d;
    if (e < N_EDGES) { s = ei[e]; d = ei[N_EDGES + e]; }
    else             { s = e - N_EDGES; d = s; }
    int pos = atomicAdd(&cur[d], 1);
    csr_src[pos] = s;
}

// ---------------------------------------------------------------------------
// GAT aggregation for one node per block: segment softmax + weighted gather.
// mode 0: out = elu(agg + bias)            (layer 1)
// mode 1: out = agg + bias + beta*gp[n]    (layer 2)
// Block: H*128 threads.
// ---------------------------------------------------------------------------
template<int H>
__global__ void gat_agg_kernel(const float* __restrict__ h,     // [N, H*128]
                               const float* __restrict__ as,    // [N, H]
                               const float* __restrict__ ad,    // [N, H]
                               const int* __restrict__ off,
                               const int* __restrict__ csr_src,
                               const float* __restrict__ bias,  // [H*128]
                               float* __restrict__ out,         // [N, H*128]
                               const float* __restrict__ gp,    // [N,128] or null
                               const float* __restrict__ beta_p,
                               int mode) {
    int n = blockIdx.x;
    int tid = threadIdx.x;
    int hd = tid >> 7, c = tid & 127;
    int o0 = off[n], o1 = off[n + 1];
    int deg = o1 - o0;
    float adn = ad[n * H + hd];
    __shared__ float red[H * 128];

    // phase 1: max logit per head
    float m = -1e30f;
    for (int j = c; j < deg; j += 128) {
        int sn = csr_src[o0 + j];
        float e = as[sn * H + hd] + adn;
        e = e > 0.0f ? e : 0.2f * e;
        m = fmaxf(m, e);
    }
    red[tid] = m; __syncthreads();
    for (int s = 64; s > 0; s >>= 1) {
        if ((tid & 127) < s) red[tid] = fmaxf(red[tid], red[tid + s]);
        __syncthreads();
    }
    m = red[hd << 7];
    __syncthreads();

    // phase 2: sum of exp
    float ssum = 0.0f;
    for (int j = c; j < deg; j += 128) {
        int sn = csr_src[o0 + j];
        float e = as[sn * H + hd] + adn;
        e = e > 0.0f ? e : 0.2f * e;
        ssum += expf(e - m);
    }
    red[tid] = ssum; __syncthreads();
    for (int s = 64; s > 0; s >>= 1) {
        if ((tid & 127) < s) red[tid] += red[tid + s];
        __syncthreads();
    }
    float inv = 1.0f / (red[hd << 7] + 1e-16f);
    __syncthreads();

    // phase 3: weighted gather
    float acc = 0.0f;
    for (int j = 0; j < deg; ++j) {
        int sn = csr_src[o0 + j];
        float e = as[sn * H + hd] + adn;
        e = e > 0.0f ? e : 0.2f * e;
        float w = expf(e - m) * inv;
        acc += w * h[sn * (H * 128) + tid];
    }
    acc += bias[tid];
    if (mode == 0) {
        acc = acc > 0.0f ? acc : expm1f(acc);
    } else {
        acc += beta_p[0] * gp[n * 128 + tid];
    }
    out[n * (H * 128) + tid] = acc;
}

// ---------------------------------------------------------------------------
extern "C" void kernel_launch(void* const* d_in, const int* in_sizes, int n_in,
                              void* d_out, int out_size, void* d_ws, size_t ws_size,
                              hipStream_t stream) {
    const float* x        = (const float*)d_in[0];
    const int*   ei       = (const int*)  d_in[1];
    const float* g        = (const float*)d_in[2];
    const float* proj_W   = (const float*)d_in[3];
    const float* proj_b   = (const float*)d_in[4];
    const float* gat1_W   = (const float*)d_in[5];
    const float* g1_as    = (const float*)d_in[6];
    const float* g1_ad    = (const float*)d_in[7];
    const float* gat1_b   = (const float*)d_in[8];
    const float* gat2_W   = (const float*)d_in[9];
    const float* g2_as    = (const float*)d_in[10];
    const float* g2_ad    = (const float*)d_in[11];
    const float* gat2_b   = (const float*)d_in[12];
    const float* dec_W    = (const float*)d_in[13];
    const float* dec_b    = (const float*)d_in[14];
    const float* beta     = (const float*)d_in[15];
    float* out = (float*)d_out;

    // workspace carve
    char* p = (char*)d_ws;
    auto alloc = [&](size_t bytes) { void* r = (void*)p; p += (bytes + 255) & ~(size_t)255; return r; };
    float* xp   = (float*)alloc((size_t)N_NODES * 128 * 4);
    float* gp   = (float*)alloc((size_t)N_NODES * 128 * 4);
    float* h1   = (float*)alloc((size_t)N_NODES * 512 * 4);
    float* helu = (float*)alloc((size_t)N_NODES * 512 * 4);
    float* h2   = (float*)alloc((size_t)N_NODES * 128 * 4);
    float* hfin = (float*)alloc((size_t)N_NODES * 128 * 4);
    float* a1s  = (float*)alloc((size_t)N_NODES * 4 * 4);
    float* a1d  = (float*)alloc((size_t)N_NODES * 4 * 4);
    float* a2s  = (float*)alloc((size_t)N_NODES * 4);
    float* a2d  = (float*)alloc((size_t)N_NODES * 4);
    int*   deg  = (int*)alloc((size_t)N_NODES * 4);
    int*   off  = (int*)alloc((size_t)(N_NODES + 1) * 4);
    int*   cur  = (int*)alloc((size_t)N_NODES * 4);
    int*   csr  = (int*)alloc((size_t)ET * 4);

    const int RWS = 8;
    const int NB  = N_NODES / RWS;   // 1250

    // proj: xp = x @ proj_W + b ; gp = g @ proj_W + b
    hipLaunchKernelGGL((gemm_rows_kernel<D_INF, 128, RWS>), dim3(NB), dim3(128),
                       RWS * D_INF * 4, stream, x, proj_W, proj_b, xp);
    hipLaunchKernelGGL((gemm_rows_kernel<D_INF, 128, RWS>), dim3(NB), dim3(128),
                       RWS * D_INF * 4, stream, g, proj_W, proj_b, gp);

    // CSR build
    hipLaunchKernelGGL(zero_int_kernel, dim3((N_NODES + 255) / 256), dim3(256), 0, stream, deg, N_NODES);
    hipLaunchKernelGGL(deg_kernel, dim3((ET + 255) / 256), dim3(256), 0, stream, ei, deg);
    hipLaunchKernelGGL(scan_kernel, dim3(1), dim3(1024), 0, stream, deg, off, cur);
    hipLaunchKernelGGL(fill_kernel, dim3((ET + 255) / 256), dim3(256), 0, stream, ei, cur, csr);

    // gat1 linear + attention logits
    hipLaunchKernelGGL((gemm_rows_kernel<128, 512, RWS>), dim3(NB), dim3(512),
                       RWS * 128 * 4, stream, xp, gat1_W, (const float*)nullptr, h1);
    hipLaunchKernelGGL(att_kernel<4>, dim3(N_NODES), dim3(512), 0, stream, h1, g1_as, g1_ad, a1s, a1d);

    // gat1 aggregate + bias + elu
    hipLaunchKernelGGL(gat_agg_kernel<4>, dim3(N_NODES), dim3(512), 0, stream,
                       h1, a1s, a1d, off, csr, gat1_b, helu,
                       (const float*)nullptr, (const float*)nullptr, 0);

    // gat2 linear + attention logits
    hipLaunchKernelGGL((gemm_rows_kernel<512, 128, RWS>), dim3(NB), dim3(128),
                       RWS * 512 * 4, stream, helu, gat2_W, (const float*)nullptr, h2);
    hipLaunchKernelGGL(att_kernel<1>, dim3(N_NODES), dim3(128), 0, stream, h2, g2_as, g2_ad, a2s, a2d);

    // gat2 aggregate + bias + beta*gp
    hipLaunchKernelGGL(gat_agg_kernel<1>, dim3(N_NODES), dim3(128), 0, stream,
                       h2, a2s, a2d, off, csr, gat2_b, hfin, gp, beta, 1);

    // decoder
    hipLaunchKernelGGL((gemm_rows_kernel<128, D_INF, RWS>), dim3(NB), dim3(768),
                       RWS * 128 * 4, stream, hfin, dec_W, dec_b, out);
}

// Round 2
// 489.196 us; speedup vs baseline: 1.0542x; 1.0542x over previous
//
#include <hip/hip_runtime.h>
#include <hip/hip_bf16.h>
#include <math.h>

#define N_NODES 10000
#define N_EDGES 160000
#define ET      (N_EDGES + N_NODES)   // with self loops
#define D_INF   768

// ---------------------------------------------------------------------------
// Row-panel GEMM: out[*, M] = in[*, K] @ W[K, M] (+ bias)
// Block = M*GROUPS threads; RWS*GROUPS rows staged in dynamic LDS.
// Inner loop reads row values as float4 over k (uniform ds_read_b128 =
// broadcast, conflict-free) -> 8 b128 per 32 FMAs -> FMA-bound.
// ---------------------------------------------------------------------------
template<int K, int M, int RWS, int GROUPS>
__global__ void gemm_kernel(const float* __restrict__ in,
                            const float* __restrict__ W,
                            const float* __restrict__ bias,
                            float* __restrict__ out) {
    constexpr int T   = M * GROUPS;
    constexpr int RPB = RWS * GROUPS;
    int row0 = blockIdx.x * RPB;
    extern __shared__ float lds[];
    const float4* in4 = reinterpret_cast<const float4*>(in + (size_t)row0 * K);
    float4* lds4 = reinterpret_cast<float4*>(lds);
    for (int i = threadIdx.x; i < RPB * K / 4; i += T) lds4[i] = in4[i];
    __syncthreads();

    int g   = threadIdx.x / M;
    int col = threadIdx.x % M;
    int rb  = g * RWS;

    float acc[RWS];
#pragma unroll
    for (int r = 0; r < RWS; ++r) acc[r] = 0.0f;

#pragma unroll 2
    for (int k = 0; k < K; k += 4) {
        float w0 = W[(size_t)(k + 0) * M + col];
        float w1 = W[(size_t)(k + 1) * M + col];
        float w2 = W[(size_t)(k + 2) * M + col];
        float w3 = W[(size_t)(k + 3) * M + col];
#pragma unroll
        for (int r = 0; r < RWS; ++r) {
            float4 rv = *reinterpret_cast<const float4*>(&lds[(rb + r) * K + k]);
            acc[r] = fmaf(rv.w, w3, fmaf(rv.z, w2, fmaf(rv.y, w1, fmaf(rv.x, w0, acc[r]))));
        }
    }

    float bb = bias ? bias[col] : 0.0f;
#pragma unroll
    for (int r = 0; r < RWS; ++r)
        out[(size_t)(row0 + rb + r) * M + col] = acc[r] + bb;
}

// ---------------------------------------------------------------------------
// Attention logits, wave-per-node: as[n,h] = sum_c h[n,h,c]*att_src[h,c]
// Block 256 = 4 waves, node = blockIdx.x*4 + wave.
// ---------------------------------------------------------------------------
template<int H>
__global__ void att_kernel(const float* __restrict__ h,
                           const float* __restrict__ att_src,
                           const float* __restrict__ att_dst,
                           float* __restrict__ as, float* __restrict__ ad) {
    constexpr int EPL = 2 * H;        // elements per lane (E = H*128, 64 lanes)
    constexpr int G   = 64 / H;       // lanes per head
    int wv = threadIdx.x >> 6, lane = threadIdx.x & 63;
    int n = blockIdx.x * 4 + wv;
    const float* hp = h + (size_t)n * (H * 128) + lane * EPL;
    const float* sp = att_src + lane * EPL;
    const float* dp = att_dst + lane * EPL;
    float ss = 0.0f, sd = 0.0f;
#pragma unroll
    for (int i = 0; i < EPL; i += 2) {
        float2 v = *reinterpret_cast<const float2*>(hp + i);
        float2 a = *reinterpret_cast<const float2*>(sp + i);
        float2 b = *reinterpret_cast<const float2*>(dp + i);
        ss += v.x * a.x + v.y * a.y;
        sd += v.x * b.x + v.y * b.y;
    }
#pragma unroll
    for (int m = G >> 1; m > 0; m >>= 1) {
        ss += __shfl_xor(ss, m, 64);
        sd += __shfl_xor(sd, m, 64);
    }
    if ((lane & (G - 1)) == 0) {
        int hd = lane / G;
        as[(size_t)n * H + hd] = ss;
        ad[(size_t)n * H + hd] = sd;
    }
}

// ---------------------------------------------------------------------------
// CSR build (by dst)
// ---------------------------------------------------------------------------
__global__ void zero_int_kernel(int* __restrict__ p, int n) {
    int i = blockIdx.x * blockDim.x + threadIdx.x;
    if (i < n) p[i] = 0;
}

__global__ void deg_kernel(const int* __restrict__ ei, int* __restrict__ deg) {
    int e = blockIdx.x * blockDim.x + threadIdx.x;
    if (e >= ET) return;
    int d = (e < N_EDGES) ? ei[N_EDGES + e] : (e - N_EDGES);
    atomicAdd(&deg[d], 1);
}

__global__ void scan_kernel(const int* __restrict__ deg,
                            int* __restrict__ off, int* __restrict__ cur) {
    __shared__ int tmp[1024];
    __shared__ int carry;
    int tid = threadIdx.x;
    if (tid == 0) carry = 0;
    __syncthreads();
    for (int base = 0; base < N_NODES; base += 1024) {
        int i = base + tid;
        int v = (i < N_NODES) ? deg[i] : 0;
        tmp[tid] = v;
        __syncthreads();
        for (int s = 1; s < 1024; s <<= 1) {
            int t = (tid >= s) ? tmp[tid - s] : 0;
            __syncthreads();
            tmp[tid] += t;
            __syncthreads();
        }
        int incl = tmp[tid];
        int ex = carry + incl - v;
        if (i < N_NODES) { off[i] = ex; cur[i] = ex; }
        __syncthreads();
        if (tid == 1023) carry += incl;
        __syncthreads();
    }
    if (tid == 0) off[N_NODES] = carry;
}

__global__ void fill_kernel(const int* __restrict__ ei,
                            int* __restrict__ cur, int* __restrict__ csr_src) {
    int e = blockIdx.x * blockDim.x + threadIdx.x;
    if (e >= ET) return;
    int s, d;
    if (e < N_EDGES) { s = ei[e]; d = ei[N_EDGES + e]; }
    else             { s = e - N_EDGES; d = s; }
    int pos = atomicAdd(&cur[d], 1);
    csr_src[pos] = s;
}

// ---------------------------------------------------------------------------
// Segment softmax, wave-per-node: per-edge ex = exp(leaky(as[src]+ad[dst])-m)
// stored to exw; per-node 1/(sum+eps) stored to inv_s. No block syncs.
// ---------------------------------------------------------------------------
template<int H>
__global__ void softmax_kernel(const float* __restrict__ as,
                               const float* __restrict__ ad,
                               const int* __restrict__ off,
                               const int* __restrict__ csr_src,
                               float* __restrict__ exw,     // [ET, H]
                               float* __restrict__ inv_s) { // [N, H]
    int wv = threadIdx.x >> 6, lane = threadIdx.x & 63;
    int n = blockIdx.x * 4 + wv;
    int o0 = off[n], o1 = off[n + 1];
    float adn[H], m[H], s[H];
#pragma unroll
    for (int h = 0; h < H; ++h) { adn[h] = ad[(size_t)n * H + h]; m[h] = -1e30f; s[h] = 0.0f; }

    for (int j = o0 + lane; j < o1; j += 64) {
        int sn = csr_src[j];
#pragma unroll
        for (int h = 0; h < H; ++h) {
            float e = as[(size_t)sn * H + h] + adn[h];
            e = e > 0.0f ? e : 0.2f * e;
            m[h] = fmaxf(m[h], e);
        }
    }
#pragma unroll
    for (int mk = 32; mk > 0; mk >>= 1)
#pragma unroll
        for (int h = 0; h < H; ++h) m[h] = fmaxf(m[h], __shfl_xor(m[h], mk, 64));

    for (int j = o0 + lane; j < o1; j += 64) {
        int sn = csr_src[j];
        float exv[H];
#pragma unroll
        for (int h = 0; h < H; ++h) {
            float e = as[(size_t)sn * H + h] + adn[h];
            e = e > 0.0f ? e : 0.2f * e;
            exv[h] = expf(e - m[h]);
            s[h] += exv[h];
        }
        if (H == 4) {
            *reinterpret_cast<float4*>(exw + (size_t)j * 4) =
                make_float4(exv[0], exv[1], exv[2 % H], exv[3 % H]);
        } else {
            exw[j] = exv[0];
        }
    }
#pragma unroll
    for (int mk = 32; mk > 0; mk >>= 1)
#pragma unroll
        for (int h = 0; h < H; ++h) s[h] += __shfl_xor(s[h], mk, 64);

    if (lane == 0) {
#pragma unroll
        for (int h = 0; h < H; ++h) inv_s[(size_t)n * H + h] = 1.0f / (s[h] + 1e-16f);
    }
}

// ---------------------------------------------------------------------------
// Weighted gather: out[n,c] = (sum_j exw[j,hd]*h[src_j, c]) * inv_s[n,hd] + ...
// No syncs, no exp; 4-wide unrolled so 4 gathers stay in flight.
// MODE 0: elu(. + bias)   MODE 1: . + bias + beta*gp
// ---------------------------------------------------------------------------
template<int H, int MODE, int NPB>
__global__ void gather_kernel(const float* __restrict__ h,
                              const float* __restrict__ exw,
                              const float* __restrict__ inv_s,
                              const int* __restrict__ off,
                              const int* __restrict__ csr_src,
                              const float* __restrict__ bias,
                              float* __restrict__ out,
                              const float* __restrict__ gp,
                              const float* __restrict__ beta_p) {
    constexpr int C = H * 128;
    int sub = threadIdx.x / C;
    int c   = threadIdx.x % C;
    int n   = blockIdx.x * NPB + sub;
    int hd  = c >> 7;
    int o0 = off[n], o1 = off[n + 1];

    float acc = 0.0f;
    int j = o0;
    for (; j + 4 <= o1; j += 4) {
        int s0 = csr_src[j + 0], s1 = csr_src[j + 1];
        int s2 = csr_src[j + 2], s3 = csr_src[j + 3];
        float w0 = exw[(size_t)(j + 0) * H + hd];
        float w1 = exw[(size_t)(j + 1) * H + hd];
        float w2 = exw[(size_t)(j + 2) * H + hd];
        float w3 = exw[(size_t)(j + 3) * H + hd];
        float v0 = h[(size_t)s0 * C + c];
        float v1 = h[(size_t)s1 * C + c];
        float v2 = h[(size_t)s2 * C + c];
        float v3 = h[(size_t)s3 * C + c];
        acc = fmaf(w0, v0, acc);
        acc = fmaf(w1, v1, acc);
        acc = fmaf(w2, v2, acc);
        acc = fmaf(w3, v3, acc);
    }
    for (; j < o1; ++j) {
        int sn = csr_src[j];
        float w = exw[(size_t)j * H + hd];
        acc = fmaf(w, h[(size_t)sn * C + c], acc);
    }

    float r = acc * inv_s[(size_t)n * H + hd] + bias[c];
    if (MODE == 0) {
        r = r > 0.0f ? r : expm1f(r);
    } else {
        r += beta_p[0] * gp[(size_t)n * 128 + c];
    }
    out[(size_t)n * C + c] = r;
}

// ---------------------------------------------------------------------------
extern "C" void kernel_launch(void* const* d_in, const int* in_sizes, int n_in,
                              void* d_out, int out_size, void* d_ws, size_t ws_size,
                              hipStream_t stream) {
    const float* x        = (const float*)d_in[0];
    const int*   ei       = (const int*)  d_in[1];
    const float* g        = (const float*)d_in[2];
    const float* proj_W   = (const float*)d_in[3];
    const float* proj_b   = (const float*)d_in[4];
    const float* gat1_W   = (const float*)d_in[5];
    const float* g1_as    = (const float*)d_in[6];
    const float* g1_ad    = (const float*)d_in[7];
    const float* gat1_b   = (const float*)d_in[8];
    const float* gat2_W   = (const float*)d_in[9];
    const float* g2_as    = (const float*)d_in[10];
    const float* g2_ad    = (const float*)d_in[11];
    const float* gat2_b   = (const float*)d_in[12];
    const float* dec_W    = (const float*)d_in[13];
    const float* dec_b    = (const float*)d_in[14];
    const float* beta     = (const float*)d_in[15];
    float* out = (float*)d_out;

    // workspace carve
    char* p = (char*)d_ws;
    auto alloc = [&](size_t bytes) { void* r = (void*)p; p += (bytes + 255) & ~(size_t)255; return r; };
    float* xp   = (float*)alloc((size_t)N_NODES * 128 * 4);
    float* gp   = (float*)alloc((size_t)N_NODES * 128 * 4);
    float* h1   = (float*)alloc((size_t)N_NODES * 512 * 4);
    float* helu = (float*)alloc((size_t)N_NODES * 512 * 4);
    float* h2   = (float*)alloc((size_t)N_NODES * 128 * 4);
    float* hfin = (float*)alloc((size_t)N_NODES * 128 * 4);
    float* a1s  = (float*)alloc((size_t)N_NODES * 4 * 4);
    float* a1d  = (float*)alloc((size_t)N_NODES * 4 * 4);
    float* a2s  = (float*)alloc((size_t)N_NODES * 4);
    float* a2d  = (float*)alloc((size_t)N_NODES * 4);
    float* is1  = (float*)alloc((size_t)N_NODES * 4 * 4);
    float* is2  = (float*)alloc((size_t)N_NODES * 4);
    float* exw4 = (float*)alloc((size_t)ET * 4 * 4);
    float* exw1 = (float*)alloc((size_t)ET * 4);
    int*   deg  = (int*)alloc((size_t)N_NODES * 4);
    int*   off  = (int*)alloc((size_t)(N_NODES + 1) * 4);
    int*   cur  = (int*)alloc((size_t)N_NODES * 4);
    int*   csr  = (int*)alloc((size_t)ET * 4);

    // --- dense: proj (x and g) ---
    // <K=768, M=128, RWS=8, GROUPS=2>: block 256, 16 rows, LDS 48KB
    hipLaunchKernelGGL((gemm_kernel<768, 128, 8, 2>), dim3(N_NODES / 16), dim3(256),
                       16 * 768 * 4, stream, x, proj_W, proj_b, xp);
    hipLaunchKernelGGL((gemm_kernel<768, 128, 8, 2>), dim3(N_NODES / 16), dim3(256),
                       16 * 768 * 4, stream, g, proj_W, proj_b, gp);

    // --- CSR build ---
    hipLaunchKernelGGL(zero_int_kernel, dim3((N_NODES + 255) / 256), dim3(256), 0, stream, deg, N_NODES);
    hipLaunchKernelGGL(deg_kernel, dim3((ET + 255) / 256), dim3(256), 0, stream, ei, deg);
    hipLaunchKernelGGL(scan_kernel, dim3(1), dim3(1024), 0, stream, deg, off, cur);
    hipLaunchKernelGGL(fill_kernel, dim3((ET + 255) / 256), dim3(256), 0, stream, ei, cur, csr);

    // --- gat1 ---
    // <K=128, M=512, RWS=16, GROUPS=1>: block 512, 16 rows, LDS 8KB
    hipLaunchKernelGGL((gemm_kernel<128, 512, 16, 1>), dim3(N_NODES / 16), dim3(512),
                       16 * 128 * 4, stream, xp, gat1_W, (const float*)nullptr, h1);
    hipLaunchKernelGGL(att_kernel<4>, dim3(N_NODES / 4), dim3(256), 0, stream,
                       h1, g1_as, g1_ad, a1s, a1d);
    hipLaunchKernelGGL(softmax_kernel<4>, dim3(N_NODES / 4), dim3(256), 0, stream,
                       a1s, a1d, off, csr, exw4, is1);
    hipLaunchKernelGGL((gather_kernel<4, 0, 1>), dim3(N_NODES), dim3(512), 0, stream,
                       h1, exw4, is1, off, csr, gat1_b, helu,
                       (const float*)nullptr, (const float*)nullptr);

    // --- gat2 ---
    // <K=512, M=128, RWS=8, GROUPS=2>: block 256, 16 rows, LDS 32KB
    hipLaunchKernelGGL((gemm_kernel<512, 128, 8, 2>), dim3(N_NODES / 16), dim3(256),
                       16 * 512 * 4, stream, helu, gat2_W, (const float*)nullptr, h2);
    hipLaunchKernelGGL(att_kernel<1>, dim3(N_NODES / 4), dim3(256), 0, stream,
                       h2, g2_as, g2_ad, a2s, a2d);
    hipLaunchKernelGGL(softmax_kernel<1>, dim3(N_NODES / 4), dim3(256), 0, stream,
                       a2s, a2d, off, csr, exw1, is2);
    hipLaunchKernelGGL((gather_kernel<1, 1, 2>), dim3(N_NODES / 2), dim3(256), 0, stream,
                       h2, exw1, is2, off, csr, gat2_b, hfin, gp, beta);

    // --- decoder ---
    // <K=128, M=768, RWS=16, GROUPS=1>: block 768, 16 rows, LDS 8KB
    hipLaunchKernelGGL((gemm_kernel<128, 768, 16, 1>), dim3(N_NODES / 16), dim3(768),
                       16 * 128 * 4, stream, hfin, dec_W, dec_b, out);
}

// Round 3
// 362.080 us; speedup vs baseline: 1.4243x; 1.3511x over previous
//
#include <hip/hip_runtime.h>
#include <math.h>

#define N_NODES 10000
#define PAD_N   10048
#define N_EDGES 160000
#define ET      (N_EDGES + N_NODES)   // with self loops

typedef unsigned short u16;
typedef __attribute__((ext_vector_type(8))) short bf16x8;
typedef __attribute__((ext_vector_type(4))) float f32x4;

__device__ __forceinline__ u16 f2bf(float f) {
    union { float f; unsigned u; } v; v.f = f;
    unsigned r = (v.u + 0x7FFFu + ((v.u >> 16) & 1u)) >> 16;
    return (u16)r;
}
__device__ __forceinline__ float bf2f(u16 b) {
    union { unsigned u; float f; } v; v.u = ((unsigned)b) << 16;
    return v.f;
}

// ---------------------------------------------------------------------------
// fp32 -> bf16 hi/lo split (same layout), vectorized by 4
// ---------------------------------------------------------------------------
__global__ void split_kernel(const float* __restrict__ in, u16* __restrict__ hi,
                             u16* __restrict__ lo, int n4) {
    int i = blockIdx.x * blockDim.x + threadIdx.x;
    if (i >= n4) return;
    float4 v = reinterpret_cast<const float4*>(in)[i];
    u16 h0 = f2bf(v.x), h1 = f2bf(v.y), h2 = f2bf(v.z), h3 = f2bf(v.w);
    ushort4 hv = make_ushort4(h0, h1, h2, h3);
    ushort4 lv = make_ushort4(f2bf(v.x - bf2f(h0)), f2bf(v.y - bf2f(h1)),
                              f2bf(v.z - bf2f(h2)), f2bf(v.w - bf2f(h3)));
    reinterpret_cast<ushort4*>(hi)[i] = hv;
    reinterpret_cast<ushort4*>(lo)[i] = lv;
}

// ---------------------------------------------------------------------------
// weight split + transpose: W[K][N] fp32 -> th/tl[N][K] bf16
// ---------------------------------------------------------------------------
__global__ void wsplit_kernel(const float* __restrict__ W, u16* __restrict__ th,
                              u16* __restrict__ tl, int K, int N) {
    int idx = blockIdx.x * blockDim.x + threadIdx.x;
    if (idx >= K * N) return;
    int k = idx / N, n = idx - k * N;
    float v = W[idx];
    u16 h = f2bf(v);
    th[(size_t)n * K + k] = h;
    tl[(size_t)n * K + k] = f2bf(v - bf2f(h));
}

// ---------------------------------------------------------------------------
// Split-bf16 MFMA GEMM: C[rows<10000][NDIM] = A[rows][K] @ B[K][NDIM] (+bias)
// A given as hi/lo bf16 row-major; B given as hi/lo bf16 TRANSPOSED [NDIM][K].
// C = Ah*Bh + Ah*Bl + Al*Bh  (fp32 accum; error ~2^-18 rel)
// Block 256 = 4 waves (2x2); wave = 32x32 = 2x2 frags of 16x16; K step 32.
// OUTMODE 0: fp32 out. OUTMODE 1: bf16 hi/lo out.
// ---------------------------------------------------------------------------
template<int K, int NDIM, int OUTMODE>
__global__ __launch_bounds__(256, 4)
void mm_kernel(const u16* __restrict__ Ah, const u16* __restrict__ Al,
               const u16* __restrict__ Bh, const u16* __restrict__ Bl,
               const float* __restrict__ bias,
               float* __restrict__ outf, u16* __restrict__ outh, u16* __restrict__ outl,
               int arowmax) {
    int lane = threadIdx.x & 63;
    int wid  = threadIdx.x >> 6;
    int wm = wid >> 1, wn = wid & 1;
    int row0 = blockIdx.x * 64 + wm * 32;
    int col0 = blockIdx.y * 64 + wn * 32;
    int lr = lane & 15;          // 16-dim index within fragment
    int lk = (lane >> 4) * 8;    // k offset within fragment

    int ra0 = min(row0 + lr,      arowmax);
    int ra1 = min(row0 + 16 + lr, arowmax);
    const u16* pa0h = Ah + (size_t)ra0 * K + lk;
    const u16* pa1h = Ah + (size_t)ra1 * K + lk;
    const u16* pa0l = Al + (size_t)ra0 * K + lk;
    const u16* pa1l = Al + (size_t)ra1 * K + lk;
    const u16* pb0h = Bh + (size_t)(col0 + lr)      * K + lk;
    const u16* pb1h = Bh + (size_t)(col0 + 16 + lr) * K + lk;
    const u16* pb0l = Bl + (size_t)(col0 + lr)      * K + lk;
    const u16* pb1l = Bl + (size_t)(col0 + 16 + lr) * K + lk;

    f32x4 acc[2][2];
#pragma unroll
    for (int i = 0; i < 2; ++i)
#pragma unroll
        for (int j = 0; j < 2; ++j) acc[i][j] = (f32x4){0.f, 0.f, 0.f, 0.f};

#pragma unroll 2
    for (int k = 0; k < K; k += 32) {
        bf16x8 a0h = *(const bf16x8*)(pa0h + k);
        bf16x8 a1h = *(const bf16x8*)(pa1h + k);
        bf16x8 a0l = *(const bf16x8*)(pa0l + k);
        bf16x8 a1l = *(const bf16x8*)(pa1l + k);
        bf16x8 b0h = *(const bf16x8*)(pb0h + k);
        bf16x8 b1h = *(const bf16x8*)(pb1h + k);
        bf16x8 b0l = *(const bf16x8*)(pb0l + k);
        bf16x8 b1l = *(const bf16x8*)(pb1l + k);

        acc[0][0] = __builtin_amdgcn_mfma_f32_16x16x32_bf16(a0h, b0h, acc[0][0], 0, 0, 0);
        acc[0][1] = __builtin_amdgcn_mfma_f32_16x16x32_bf16(a0h, b1h, acc[0][1], 0, 0, 0);
        acc[1][0] = __builtin_amdgcn_mfma_f32_16x16x32_bf16(a1h, b0h, acc[1][0], 0, 0, 0);
        acc[1][1] = __builtin_amdgcn_mfma_f32_16x16x32_bf16(a1h, b1h, acc[1][1], 0, 0, 0);
        acc[0][0] = __builtin_amdgcn_mfma_f32_16x16x32_bf16(a0h, b0l, acc[0][0], 0, 0, 0);
        acc[0][1] = __builtin_amdgcn_mfma_f32_16x16x32_bf16(a0h, b1l, acc[0][1], 0, 0, 0);
        acc[1][0] = __builtin_amdgcn_mfma_f32_16x16x32_bf16(a1h, b0l, acc[1][0], 0, 0, 0);
        acc[1][1] = __builtin_amdgcn_mfma_f32_16x16x32_bf16(a1h, b1l, acc[1][1], 0, 0, 0);
        acc[0][0] = __builtin_amdgcn_mfma_f32_16x16x32_bf16(a0l, b0h, acc[0][0], 0, 0, 0);
        acc[0][1] = __builtin_amdgcn_mfma_f32_16x16x32_bf16(a0l, b1h, acc[0][1], 0, 0, 0);
        acc[1][0] = __builtin_amdgcn_mfma_f32_16x16x32_bf16(a1l, b0h, acc[1][0], 0, 0, 0);
        acc[1][1] = __builtin_amdgcn_mfma_f32_16x16x32_bf16(a1l, b1h, acc[1][1], 0, 0, 0);
    }

    int orq = (lane >> 4) * 4;
#pragma unroll
    for (int fm = 0; fm < 2; ++fm)
#pragma unroll
        for (int fn = 0; fn < 2; ++fn) {
            int oc = col0 + fn * 16 + lr;
            float bb = bias ? bias[oc] : 0.0f;
#pragma unroll
            for (int i = 0; i < 4; ++i) {
                int orow = row0 + fm * 16 + orq + i;
                if (orow < N_NODES) {
                    float r = acc[fm][fn][i] + bb;
                    if (OUTMODE == 0) {
                        outf[(size_t)orow * NDIM + oc] = r;
                    } else {
                        u16 hh = f2bf(r);
                        outh[(size_t)orow * NDIM + oc] = hh;
                        outl[(size_t)orow * NDIM + oc] = f2bf(r - bf2f(hh));
                    }
                }
            }
        }
}

// ---------------------------------------------------------------------------
// Attention logits, wave-per-node
// ---------------------------------------------------------------------------
template<int H>
__global__ void att_kernel(const float* __restrict__ h,
                           const float* __restrict__ att_src,
                           const float* __restrict__ att_dst,
                           float* __restrict__ as, float* __restrict__ ad) {
    constexpr int EPL = 2 * H;
    constexpr int G   = 64 / H;
    int wv = threadIdx.x >> 6, lane = threadIdx.x & 63;
    int n = blockIdx.x * 4 + wv;
    const float* hp = h + (size_t)n * (H * 128) + lane * EPL;
    const float* sp = att_src + lane * EPL;
    const float* dp = att_dst + lane * EPL;
    float ss = 0.0f, sd = 0.0f;
#pragma unroll
    for (int i = 0; i < EPL; i += 2) {
        float2 v = *reinterpret_cast<const float2*>(hp + i);
        float2 a = *reinterpret_cast<const float2*>(sp + i);
        float2 b = *reinterpret_cast<const float2*>(dp + i);
        ss += v.x * a.x + v.y * a.y;
        sd += v.x * b.x + v.y * b.y;
    }
#pragma unroll
    for (int m = G >> 1; m > 0; m >>= 1) {
        ss += __shfl_xor(ss, m, 64);
        sd += __shfl_xor(sd, m, 64);
    }
    if ((lane & (G - 1)) == 0) {
        int hd = lane / G;
        as[(size_t)n * H + hd] = ss;
        ad[(size_t)n * H + hd] = sd;
    }
}

// ---------------------------------------------------------------------------
// CSR build (by dst)
// ---------------------------------------------------------------------------
__global__ void zero_int_kernel(int* __restrict__ p, int n) {
    int i = blockIdx.x * blockDim.x + threadIdx.x;
    if (i < n) p[i] = 0;
}

__global__ void deg_kernel(const int* __restrict__ ei, int* __restrict__ deg) {
    int e = blockIdx.x * blockDim.x + threadIdx.x;
    if (e >= ET) return;
    int d = (e < N_EDGES) ? ei[N_EDGES + e] : (e - N_EDGES);
    atomicAdd(&deg[d], 1);
}

__global__ void scan_kernel(const int* __restrict__ deg,
                            int* __restrict__ off, int* __restrict__ cur) {
    __shared__ int tmp[1024];
    __shared__ int carry;
    int tid = threadIdx.x;
    if (tid == 0) carry = 0;
    __syncthreads();
    for (int base = 0; base < N_NODES; base += 1024) {
        int i = base + tid;
        int v = (i < N_NODES) ? deg[i] : 0;
        tmp[tid] = v;
        __syncthreads();
        for (int s = 1; s < 1024; s <<= 1) {
            int t = (tid >= s) ? tmp[tid - s] : 0;
            __syncthreads();
            tmp[tid] += t;
            __syncthreads();
        }
        int incl = tmp[tid];
        int ex = carry + incl - v;
        if (i < N_NODES) { off[i] = ex; cur[i] = ex; }
        __syncthreads();
        if (tid == 1023) carry += incl;
        __syncthreads();
    }
    if (tid == 0) off[N_NODES] = carry;
}

__global__ void fill_kernel(const int* __restrict__ ei,
                            int* __restrict__ cur, int* __restrict__ csr_src) {
    int e = blockIdx.x * blockDim.x + threadIdx.x;
    if (e >= ET) return;
    int s, d;
    if (e < N_EDGES) { s = ei[e]; d = ei[N_EDGES + e]; }
    else             { s = e - N_EDGES; d = s; }
    int pos = atomicAdd(&cur[d], 1);
    csr_src[pos] = s;
}

// ---------------------------------------------------------------------------
// Segment softmax, wave-per-node
// ---------------------------------------------------------------------------
template<int H>
__global__ void softmax_kernel(const float* __restrict__ as,
                               const float* __restrict__ ad,
                               const int* __restrict__ off,
                               const int* __restrict__ csr_src,
                               float* __restrict__ exw,     // [ET, H]
                               float* __restrict__ inv_s) { // [N, H]
    int wv = threadIdx.x >> 6, lane = threadIdx.x & 63;
    int n = blockIdx.x * 4 + wv;
    int o0 = off[n], o1 = off[n + 1];
    float adn[H], m[H], s[H];
#pragma unroll
    for (int h = 0; h < H; ++h) { adn[h] = ad[(size_t)n * H + h]; m[h] = -1e30f; s[h] = 0.0f; }

    for (int j = o0 + lane; j < o1; j += 64) {
        int sn = csr_src[j];
#pragma unroll
        for (int h = 0; h < H; ++h) {
            float e = as[(size_t)sn * H + h] + adn[h];
            e = e > 0.0f ? e : 0.2f * e;
            m[h] = fmaxf(m[h], e);
        }
    }
#pragma unroll
    for (int mk = 32; mk > 0; mk >>= 1)
#pragma unroll
        for (int h = 0; h < H; ++h) m[h] = fmaxf(m[h], __shfl_xor(m[h], mk, 64));

    for (int j = o0 + lane; j < o1; j += 64) {
        int sn = csr_src[j];
        float exv[H];
#pragma unroll
        for (int h = 0; h < H; ++h) {
            float e = as[(size_t)sn * H + h] + adn[h];
            e = e > 0.0f ? e : 0.2f * e;
            exv[h] = expf(e - m[h]);
            s[h] += exv[h];
        }
        if (H == 4) {
            *reinterpret_cast<float4*>(exw + (size_t)j * 4) =
                make_float4(exv[0], exv[1], exv[2 % H], exv[3 % H]);
        } else {
            exw[j] = exv[0];
        }
    }
#pragma unroll
    for (int mk = 32; mk > 0; mk >>= 1)
#pragma unroll
        for (int h = 0; h < H; ++h) s[h] += __shfl_xor(s[h], mk, 64);

    if (lane == 0) {
#pragma unroll
        for (int h = 0; h < H; ++h) inv_s[(size_t)n * H + h] = 1.0f / (s[h] + 1e-16f);
    }
}

// ---------------------------------------------------------------------------
// Weighted gather; epilogue writes bf16 hi/lo (feeds next GEMM).
// MODE 0: elu(. + bias)   MODE 1: . + bias + beta*gp
// ---------------------------------------------------------------------------
template<int H, int MODE, int NPB>
__global__ void gather_kernel(const float* __restrict__ h,
                              const float* __restrict__ exw,
                              const float* __restrict__ inv_s,
                              const int* __restrict__ off,
                              const int* __restrict__ csr_src,
                              const float* __restrict__ bias,
                              u16* __restrict__ outh, u16* __restrict__ outl,
                              const float* __restrict__ gp,
                              const float* __restrict__ beta_p) {
    constexpr int C = H * 128;
    int sub = threadIdx.x / C;
    int c   = threadIdx.x % C;
    int n   = blockIdx.x * NPB + sub;
    int hd  = c >> 7;
    int o0 = off[n], o1 = off[n + 1];

    float acc = 0.0f;
    int j = o0;
    for (; j + 4 <= o1; j += 4) {
        int s0 = csr_src[j + 0], s1 = csr_src[j + 1];
        int s2 = csr_src[j + 2], s3 = csr_src[j + 3];
        float w0 = exw[(size_t)(j + 0) * H + hd];
        float w1 = exw[(size_t)(j + 1) * H + hd];
        float w2 = exw[(size_t)(j + 2) * H + hd];
        float w3 = exw[(size_t)(j + 3) * H + hd];
        float v0 = h[(size_t)s0 * C + c];
        float v1 = h[(size_t)s1 * C + c];
        float v2 = h[(size_t)s2 * C + c];
        float v3 = h[(size_t)s3 * C + c];
        acc = fmaf(w0, v0, acc);
        acc = fmaf(w1, v1, acc);
        acc = fmaf(w2, v2, acc);
        acc = fmaf(w3, v3, acc);
    }
    for (; j < o1; ++j) {
        int sn = csr_src[j];
        float w = exw[(size_t)j * H + hd];
        acc = fmaf(w, h[(size_t)sn * C + c], acc);
    }

    float r = acc * inv_s[(size_t)n * H + hd] + bias[c];
    if (MODE == 0) {
        r = r > 0.0f ? r : expm1f(r);
    } else {
        r += beta_p[0] * gp[(size_t)n * 128 + c];
    }
    u16 hh = f2bf(r);
    outh[(size_t)n * C + c] = hh;
    outl[(size_t)n * C + c] = f2bf(r - bf2f(hh));
}

// ---------------------------------------------------------------------------
extern "C" void kernel_launch(void* const* d_in, const int* in_sizes, int n_in,
                              void* d_out, int out_size, void* d_ws, size_t ws_size,
                              hipStream_t stream) {
    const float* x      = (const float*)d_in[0];
    const int*   ei     = (const int*)  d_in[1];
    const float* g      = (const float*)d_in[2];
    const float* proj_W = (const float*)d_in[3];
    const float* proj_b = (const float*)d_in[4];
    const float* gat1_W = (const float*)d_in[5];
    const float* g1_as  = (const float*)d_in[6];
    const float* g1_ad  = (const float*)d_in[7];
    const float* gat1_b = (const float*)d_in[8];
    const float* gat2_W = (const float*)d_in[9];
    const float* g2_as  = (const float*)d_in[10];
    const float* g2_ad  = (const float*)d_in[11];
    const float* gat2_b = (const float*)d_in[12];
    const float* dec_W  = (const float*)d_in[13];
    const float* dec_b  = (const float*)d_in[14];
    const float* beta   = (const float*)d_in[15];
    float* out = (float*)d_out;

    // ---- workspace carve (with phase-based aliasing) ----
    char* p = (char*)d_ws;
    auto alloc = [&](size_t b) { void* r = (void*)p; p += (b + 255) & ~(size_t)255; return r; };
    // R1: x-split, then g-split, then helu hi/lo (10,289,152 B each <= 15,360,000)
    u16*   abh  = (u16*)alloc((size_t)N_NODES * 768 * 2);
    u16*   abl  = (u16*)alloc((size_t)N_NODES * 768 * 2);
    // R2: h1 fp32, later h2 fp32 + hfin hi/lo
    float* h1   = (float*)alloc((size_t)PAD_N * 512 * 4);
    u16*   xph  = (u16*)alloc((size_t)PAD_N * 128 * 2);
    u16*   xpl  = (u16*)alloc((size_t)PAD_N * 128 * 2);
    float* gp   = (float*)alloc((size_t)PAD_N * 128 * 4);
    u16*   pwh  = (u16*)alloc(768 * 128 * 2);
    u16*   pwl  = (u16*)alloc(768 * 128 * 2);
    u16*   w1h  = (u16*)alloc(128 * 512 * 2);
    u16*   w1l  = (u16*)alloc(128 * 512 * 2);
    u16*   w2h  = (u16*)alloc(512 * 128 * 2);
    u16*   w2l  = (u16*)alloc(512 * 128 * 2);
    u16*   wdh  = (u16*)alloc(128 * 768 * 2);
    u16*   wdl  = (u16*)alloc(128 * 768 * 2);
    float* a1s  = (float*)alloc((size_t)N_NODES * 4 * 4);
    float* a1d  = (float*)alloc((size_t)N_NODES * 4 * 4);
    float* a2s  = (float*)alloc((size_t)N_NODES * 4);
    float* a2d  = (float*)alloc((size_t)N_NODES * 4);
    float* is1  = (float*)alloc((size_t)N_NODES * 4 * 4);
    float* is2  = (float*)alloc((size_t)N_NODES * 4);
    float* exw4 = (float*)alloc((size_t)ET * 4 * 4);
    float* exw1 = (float*)alloc((size_t)ET * 4);
    int*   deg  = (int*)alloc((size_t)N_NODES * 4);
    int*   off  = (int*)alloc((size_t)(N_NODES + 1) * 4);
    int*   cur  = (int*)alloc((size_t)N_NODES * 4);
    int*   csr  = (int*)alloc((size_t)ET * 4);
    // aliases
    u16*   heluh = abh;                 // [PAD_N][512] bf16, after g-split is dead
    u16*   helul = abl;
    float* h2    = h1;                  // [PAD_N][128] fp32, after h1 is dead
    u16*   hfinh = (u16*)((char*)h1 + (size_t)PAD_N * 128 * 4);
    u16*   hfinl = (u16*)((char*)h1 + (size_t)PAD_N * 128 * 4 + (size_t)PAD_N * 128 * 2);

    const int GX = (N_NODES + 63) / 64;   // 157

    // ---- weight splits (transposed) ----
    hipLaunchKernelGGL(wsplit_kernel, dim3((768 * 128 + 255) / 256), dim3(256), 0, stream,
                       proj_W, pwh, pwl, 768, 128);
    hipLaunchKernelGGL(wsplit_kernel, dim3((128 * 512 + 255) / 256), dim3(256), 0, stream,
                       gat1_W, w1h, w1l, 128, 512);
    hipLaunchKernelGGL(wsplit_kernel, dim3((512 * 128 + 255) / 256), dim3(256), 0, stream,
                       gat2_W, w2h, w2l, 512, 128);
    hipLaunchKernelGGL(wsplit_kernel, dim3((128 * 768 + 255) / 256), dim3(256), 0, stream,
                       dec_W, wdh, wdl, 128, 768);

    // ---- CSR build ----
    hipLaunchKernelGGL(zero_int_kernel, dim3((N_NODES + 255) / 256), dim3(256), 0, stream, deg, N_NODES);
    hipLaunchKernelGGL(deg_kernel, dim3((ET + 255) / 256), dim3(256), 0, stream, ei, deg);
    hipLaunchKernelGGL(scan_kernel, dim3(1), dim3(1024), 0, stream, deg, off, cur);
    hipLaunchKernelGGL(fill_kernel, dim3((ET + 255) / 256), dim3(256), 0, stream, ei, cur, csr);

    // ---- proj(x) -> xp hi/lo ----
    hipLaunchKernelGGL(split_kernel, dim3(7500), dim3(256), 0, stream,
                       x, abh, abl, N_NODES * 768 / 4);
    hipLaunchKernelGGL((mm_kernel<768, 128, 1>), dim3(GX, 2), dim3(256), 0, stream,
                       abh, abl, pwh, pwl, proj_b,
                       (float*)nullptr, xph, xpl, N_NODES - 1);

    // ---- proj(g) -> gp fp32 ----
    hipLaunchKernelGGL(split_kernel, dim3(7500), dim3(256), 0, stream,
                       g, abh, abl, N_NODES * 768 / 4);
    hipLaunchKernelGGL((mm_kernel<768, 128, 0>), dim3(GX, 2), dim3(256), 0, stream,
                       abh, abl, pwh, pwl, proj_b,
                       gp, (u16*)nullptr, (u16*)nullptr, N_NODES - 1);

    // ---- gat1 linear: h1 = xp @ W1 (fp32) ----
    hipLaunchKernelGGL((mm_kernel<128, 512, 0>), dim3(GX, 8), dim3(256), 0, stream,
                       xph, xpl, w1h, w1l, (const float*)nullptr,
                       h1, (u16*)nullptr, (u16*)nullptr, PAD_N - 1);
    hipLaunchKernelGGL(att_kernel<4>, dim3(N_NODES / 4), dim3(256), 0, stream,
                       h1, g1_as, g1_ad, a1s, a1d);
    hipLaunchKernelGGL(softmax_kernel<4>, dim3(N_NODES / 4), dim3(256), 0, stream,
                       a1s, a1d, off, csr, exw4, is1);
    hipLaunchKernelGGL((gather_kernel<4, 0, 1>), dim3(N_NODES), dim3(512), 0, stream,
                       h1, exw4, is1, off, csr, gat1_b, heluh, helul,
                       (const float*)nullptr, (const float*)nullptr);

    // ---- gat2 linear: h2 = helu @ W2 (fp32) ----
    hipLaunchKernelGGL((mm_kernel<512, 128, 0>), dim3(GX, 2), dim3(256), 0, stream,
                       heluh, helul, w2h, w2l, (const float*)nullptr,
                       h2, (u16*)nullptr, (u16*)nullptr, PAD_N - 1);
    hipLaunchKernelGGL(att_kernel<1>, dim3(N_NODES / 4), dim3(256), 0, stream,
                       h2, g2_as, g2_ad, a2s, a2d);
    hipLaunchKernelGGL(softmax_kernel<1>, dim3(N_NODES / 4), dim3(256), 0, stream,
                       a2s, a2d, off, csr, exw1, is2);
    hipLaunchKernelGGL((gather_kernel<1, 1, 2>), dim3(N_NODES / 2), dim3(256), 0, stream,
                       h2, exw1, is2, off, csr, gat2_b, hfinh, hfinl, gp, beta);

    // ---- decoder: out = hfin @ dec_W + b (fp32 -> d_out) ----
    hipLaunchKernelGGL((mm_kernel<128, 768, 0>), dim3(GX, 12), dim3(256), 0, stream,
                       hfinh, hfinl, wdh, wdl, dec_b,
                       out, (u16*)nullptr, (u16*)nullptr, PAD_N - 1);
}